// Round 1
// baseline (3333.340 us; speedup 1.0000x reference)
//
#include <hip/hip_runtime.h>

typedef unsigned int u32;
typedef unsigned short u16;
typedef float floatx4 __attribute__((ext_vector_type(4)));
typedef __bf16 bf16x8 __attribute__((ext_vector_type(8)));
typedef _Float16 half2v __attribute__((ext_vector_type(2)));

#define DEV __device__ __forceinline__

DEV u16 f2bf(float f){
  u32 u = __builtin_bit_cast(u32, f);
  u += 0x7FFFu + ((u >> 16) & 1u);
  return (u16)(u >> 16);
}
DEV float bf2f(u16 h){ u32 u = ((u32)h) << 16; return __builtin_bit_cast(float, u); }
DEV u16 f2h_bits(float f){ return __builtin_bit_cast(u16, (_Float16)f); }
DEV float h_bits2f(u16 h){ return (float)__builtin_bit_cast(_Float16, h); }
DEV u32 packh2(float a, float b){ return (u32)f2h_bits(a) | ((u32)f2h_bits(b) << 16); }
DEV float fdot2u(u32 a, u32 b, float c){
  return __builtin_amdgcn_fdot2(__builtin_bit_cast(half2v, a), __builtin_bit_cast(half2v, b), c, false);
}
DEV float qadd_xor1(float x){
  int y = __builtin_amdgcn_update_dpp(0, __builtin_bit_cast(int, x), 0xB1, 0xF, 0xF, true);
  return x + __builtin_bit_cast(float, y);
}
DEV float qadd_xor2(float x){
  int y = __builtin_amdgcn_update_dpp(0, __builtin_bit_cast(int, x), 0x4E, 0xF, 0xF, true);
  return x + __builtin_bit_cast(float, y);
}
DEV float sigm(float x){ return 1.f / (1.f + __expf(-x)); }
DEV float tanh_(float x){
  float ax = fabsf(x);
  float e = __expf(-2.f * ax);
  float r = (1.f - e) / (1.f + e);
  return x < 0.f ? -r : r;
}

// ---------------- prep kernels ----------------

__global__ __launch_bounds__(256) void conv_bf16_k(const float* __restrict__ src, u16* __restrict__ dst, int n){
  for (int i = blockIdx.x * 256 + threadIdx.x; i < n; i += gridDim.x * 256)
    dst[i] = f2bf(src[i]);
}

// Wt[n][k] (n = dir*1280 + g*256 + h, k = i), bf16; biasWU[n] = bW+bU
__global__ __launch_bounds__(256) void prep_wt_k(const float* __restrict__ Wf, const float* __restrict__ Wb,
                                                 const float* __restrict__ bWf, const float* __restrict__ bWb,
                                                 const float* __restrict__ bUf, const float* __restrict__ bUb,
                                                 u16* __restrict__ Wt, float* __restrict__ biasWU){
  int idx = blockIdx.x * 256 + threadIdx.x;
  if (idx >= 2560 * 256) return;
  int n = idx >> 8, k = idx & 255;
  int dir = n / 1280, rr = n - dir * 1280, g = rr >> 8, hc = rr & 255;
  const float* W = dir ? Wb : Wf;
  Wt[idx] = f2bf(W[(g * 256 + k) * 256 + hc]);
  if (k == 0)
    biasWU[n] = (dir ? bWb : bWf)[g * 256 + hc] + (dir ? bUb : bUf)[g * 256 + hc];
}

// Upk[dh][pm(160)][t(512)] : packed f16 pair (U[k][col], U[k+1][col])
__global__ __launch_bounds__(256) void prep_upk_k(const float* __restrict__ Uf, const float* __restrict__ Ub,
                                                  u32* __restrict__ Upk){
  int i = blockIdx.x * 256 + threadIdx.x;
  if (i >= 4 * 160 * 512) return;
  int t = i & 511;
  int rest = i >> 9;
  int pm = rest % 160, dh = rest / 160;
  int dir = dh >> 1, half = dh & 1;
  int p = pm >> 5, m = pm & 31;
  int w = t >> 6, l = t & 63, c = l >> 2, kq = l & 3;
  int jl = w * 16 + c;
  int j = half * 128 + jl;
  int k = kq * 64 + 2 * m;
  const float* U = dir ? Ub : Uf;
  float v0 = U[(p * 256 + k) * 256 + j];
  float v1 = U[(p * 256 + k + 1) * 256 + j];
  Upk[i] = packh2(v0, v1);
}

// Vt[bh][d][kt] from qkv[b][kt][1024 + h*128 + d]
__global__ __launch_bounds__(256) void transpose_v_k(const u16* __restrict__ qkv, u16* __restrict__ Vt){
  __shared__ u16 tile[32][33];
  int bh = blockIdx.x, bb = bh >> 2, h = bh & 3;
  int kt0 = blockIdx.y << 5, d0 = blockIdx.z << 5;
  int tx = threadIdx.x, ty = threadIdx.y;
  for (int i = ty; i < 32; i += 8)
    tile[i][tx] = qkv[(size_t)(bb * 512 + kt0 + i) * 1536 + 1024 + h * 128 + d0 + tx];
  __syncthreads();
  for (int i = ty; i < 32; i += 8)
    Vt[((size_t)bh * 128 + d0 + i) * 512 + kt0 + tx] = tile[tx][i];
}

// ---------------- GEMM (A[M,K] row-major bf16, Bt[N,K] row-major bf16) ----------------
// OM: 0=f32, 1=bf16, 2=f16

template<int OM>
__global__ __launch_bounds__(256) void gemm_bt(const u16* __restrict__ A, const u16* __restrict__ Bt,
                                               void* __restrict__ C, const float* __restrict__ bias,
                                               int M, int N, int K, int lda, int ldb, int ldc,
                                               long long aB1, long long aB2, long long bB1, long long bB2,
                                               long long cB1, long long cB2, int nb2, float scale){
  int tilesN = N >> 7;
  int bz = blockIdx.y;
  int b1 = bz / nb2, b2 = bz - b1 * nb2;
  const u16* Ab = A + (size_t)(b1 * aB1 + b2 * aB2);
  const u16* Bb = Bt + (size_t)(b1 * bB1 + b2 * bB2);
  size_t cOff = (size_t)(b1 * cB1 + b2 * cB2);
  int tm = blockIdx.x / tilesN, tn = blockIdx.x - tm * tilesN;
  int m0 = tm << 7, n0 = tn << 7;
  __shared__ u16 As[128 * 64];
  __shared__ u16 Bs[128 * 64];
  int t = threadIdx.x;
  int wave = t >> 6, lane = t & 63;
  int wr = wave >> 1, wc = wave & 1;
  int l15 = lane & 15, l4 = lane >> 4;
  floatx4 acc[4][4] = {};
  for (int k0 = 0; k0 < K; k0 += 64){
    #pragma unroll
    for (int i = 0; i < 4; i++){
      int chunk = t + (i << 8);
      int r = chunk >> 3, cx = chunk & 7;
      int sc = ((cx ^ (r & 7)) << 3);
      *(uint4*)(&As[(r << 6) + sc]) = *(const uint4*)(&Ab[(size_t)(m0 + r) * lda + k0 + (cx << 3)]);
      *(uint4*)(&Bs[(r << 6) + sc]) = *(const uint4*)(&Bb[(size_t)(n0 + r) * ldb + k0 + (cx << 3)]);
    }
    __syncthreads();
    #pragma unroll
    for (int kk = 0; kk < 2; kk++){
      bf16x8 af[4], bf[4];
      int co = (kk << 2) + l4;
      #pragma unroll
      for (int mi = 0; mi < 4; mi++){
        int r = (wr << 6) + (mi << 4) + l15;
        af[mi] = __builtin_bit_cast(bf16x8, *(const uint4*)(&As[(r << 6) + ((co ^ (r & 7)) << 3)]));
      }
      #pragma unroll
      for (int ni = 0; ni < 4; ni++){
        int r = (wc << 6) + (ni << 4) + l15;
        bf[ni] = __builtin_bit_cast(bf16x8, *(const uint4*)(&Bs[(r << 6) + ((co ^ (r & 7)) << 3)]));
      }
      #pragma unroll
      for (int mi = 0; mi < 4; mi++)
        #pragma unroll
        for (int ni = 0; ni < 4; ni++)
          acc[mi][ni] = __builtin_amdgcn_mfma_f32_16x16x32_bf16(af[mi], bf[ni], acc[mi][ni], 0, 0, 0);
    }
    __syncthreads();
  }
  #pragma unroll
  for (int mi = 0; mi < 4; mi++){
    int rowb = m0 + (wr << 6) + (mi << 4) + (l4 << 2);
    #pragma unroll
    for (int ni = 0; ni < 4; ni++){
      int col = n0 + (wc << 6) + (ni << 4) + l15;
      float bv = bias ? bias[col] : 0.f;
      #pragma unroll
      for (int r = 0; r < 4; r++){
        float val = acc[mi][ni][r] * scale + bv;
        size_t off = cOff + (size_t)(rowb + r) * ldc + col;
        if (OM == 0) ((float*)C)[off] = val;
        else if (OM == 1) ((u16*)C)[off] = f2bf(val);
        else ((u16*)C)[off] = f2h_bits(val);
      }
    }
  }
}

// ---------------- LSTM recurrence ----------------
// 128 WGs = dir(2) x batch(32) x half(2); 512 threads; U half register-resident (f16 pairs).
// h_lds padded stride-36 per kq-block to avoid bank conflicts.

__global__ __launch_bounds__(512) void lstm_rec(const u16* __restrict__ xg, const u32* __restrict__ Upk,
                                                const float* __restrict__ dw, u16* __restrict__ hcat,
                                                u32* __restrict__ h_x, u32* __restrict__ flags){
  int idx = blockIdx.x;
  int half = idx >> 6, dirb = idx & 63, dir = dirb >> 5, b = dirb & 31;
  int pidx = idx ^ 64;
  int dh = dir * 2 + half;
  int t = threadIdx.x;
  int w = t >> 6, l = t & 63, c = l >> 2, kq = l & 3;
  __shared__ __align__(16) u32 h_lds[144];
  __shared__ float gbuf[640];
  __shared__ u16 htmp[128];
  if (t < 144) h_lds[t] = 0;
  u32 u[160];
  #pragma unroll
  for (int pm = 0; pm < 160; pm++) u[pm] = Upk[(size_t)(dh * 160 + pm) * 512 + t];
  int jl = (w << 4) + c;
  int xbase = dir * 1280 + half * 128 + jl;
  float cst = 0.f;
  __syncthreads();
  for (int step = 0; step < 512; step++){
    int ts = (dir == 0) ? step : 511 - step;
    const u16* xr = xg + (size_t)(b * 512 + ts) * 2560 + xbase;
    float a5[5] = {0.f, 0.f, 0.f, 0.f, 0.f};
    #pragma unroll
    for (int mb = 0; mb < 2; mb++){
      u32 hr[16];
      #pragma unroll
      for (int i = 0; i < 4; i++){
        uint4 v = *(const uint4*)(&h_lds[kq * 36 + (mb << 4) + (i << 2)]);
        hr[(i << 2)] = v.x; hr[(i << 2) + 1] = v.y; hr[(i << 2) + 2] = v.z; hr[(i << 2) + 3] = v.w;
      }
      #pragma unroll
      for (int p = 0; p < 5; p++)
        #pragma unroll
        for (int m = 0; m < 16; m++)
          a5[p] = fdot2u(hr[m], u[p * 32 + (mb << 4) + m], a5[p]);
    }
    float g5[5];
    #pragma unroll
    for (int p = 0; p < 5; p++){
      float a = a5[p];
      a = qadd_xor1(a);
      a = qadd_xor2(a);
      g5[p] = a + h_bits2f(xr[p << 8]);
    }
    if (kq == 0){
      #pragma unroll
      for (int p = 0; p < 5; p++) gbuf[(p << 7) + jl] = g5[p];
    }
    __syncthreads();                       // bar1
    if (t < 128){
      float gi = gbuf[t], gf = gbuf[128 + t], go = gbuf[256 + t], gc = gbuf[384 + t], gs = gbuf[512 + t];
      float dwv = dw[(size_t)(b * 512 + ts) * 256 + half * 128 + t];
      float iv = sigm(gi), fv = sigm(gf), ov = sigm(go);
      float ch = tanh_(gc);
      float sv = sigm(gs) * dwv;
      cst = fv * cst + iv * ch * sv;
      float h = ov * tanh_(cst);
      htmp[t] = f2h_bits(h);
      hcat[(size_t)(b * 512 + ts) * 512 + dir * 256 + half * 128 + t] = f2bf(h);
    }
    __syncthreads();                       // bar2
    if (t < 64){
      u32 pr = ((const u32*)htmp)[t];
      int kp = (half << 6) + t;
      h_lds[(kp >> 5) * 36 + (kp & 31)] = pr;
      __hip_atomic_store(&h_x[((idx << 1) + (step & 1)) * 64 + t], pr, __ATOMIC_RELAXED, __HIP_MEMORY_SCOPE_AGENT);
    }
    __syncthreads();                       // bar3 (drains stores)
    if (t == 0)
      __hip_atomic_store(&flags[idx], (u32)(step + 1), __ATOMIC_RELEASE, __HIP_MEMORY_SCOPE_AGENT);
    if (w == 2 && step < 511){
      int guard = 0;
      while (__hip_atomic_load(&flags[pidx], __ATOMIC_ACQUIRE, __HIP_MEMORY_SCOPE_AGENT) < (u32)(step + 1)){
        __builtin_amdgcn_s_sleep(1);
        if (++guard > (1 << 14)) break;
      }
      u32 pv = __hip_atomic_load(&h_x[((pidx << 1) + (step & 1)) * 64 + l], __ATOMIC_RELAXED, __HIP_MEMORY_SCOPE_AGENT);
      int kp = ((1 - half) << 6) + l;
      h_lds[(kp >> 5) * 36 + (kp & 31)] = pv;
    }
    __syncthreads();                       // bar4
  }
}

// ---------------- softmax (in-place bf16 rows of 512) ----------------

__global__ __launch_bounds__(256) void softmax_rows(u16* __restrict__ S){
  int row = blockIdx.x * 4 + (threadIdx.x >> 6);
  int l = threadIdx.x & 63;
  u16* r = S + (size_t)row * 512;
  uint4 v = *(const uint4*)(r + l * 8);
  u32 wsv[4] = {v.x, v.y, v.z, v.w};
  float f[8];
  #pragma unroll
  for (int i = 0; i < 4; i++){
    f[2 * i] = bf2f((u16)(wsv[i] & 0xFFFF));
    f[2 * i + 1] = bf2f((u16)(wsv[i] >> 16));
  }
  float mx = f[0];
  #pragma unroll
  for (int i = 1; i < 8; i++) mx = fmaxf(mx, f[i]);
  for (int m = 1; m < 64; m <<= 1) mx = fmaxf(mx, __shfl_xor(mx, m, 64));
  float e[8], s = 0.f;
  #pragma unroll
  for (int i = 0; i < 8; i++){ e[i] = __expf(f[i] - mx); s += e[i]; }
  for (int m = 1; m < 64; m <<= 1) s += __shfl_xor(s, m, 64);
  float inv = 1.f / s;
  uint4 o;
  u32 ov[4];
  #pragma unroll
  for (int i = 0; i < 4; i++)
    ov[i] = (u32)f2bf(e[2 * i] * inv) | ((u32)f2bf(e[2 * i + 1] * inv) << 16);
  o.x = ov[0]; o.y = ov[1]; o.z = ov[2]; o.w = ov[3];
  *(uint4*)(r + l * 8) = o;
}

// ---------------- layernorm (rows of 512, f32) ----------------

__global__ __launch_bounds__(256) void ln_rows(const float* __restrict__ X, const float* __restrict__ g,
                                               const float* __restrict__ be, float* __restrict__ out){
  int row = blockIdx.x * 4 + (threadIdx.x >> 6);
  int l = threadIdx.x & 63;
  const floatx4* p = (const floatx4*)(X + (size_t)row * 512);
  floatx4 aa = p[l * 2], bb = p[l * 2 + 1];
  float v[8];
  #pragma unroll
  for (int i = 0; i < 4; i++){ v[i] = aa[i]; v[4 + i] = bb[i]; }
  float s = 0.f, s2 = 0.f;
  #pragma unroll
  for (int i = 0; i < 8; i++){ s += v[i]; s2 += v[i] * v[i]; }
  for (int m = 1; m < 64; m <<= 1){ s += __shfl_xor(s, m, 64); s2 += __shfl_xor(s2, m, 64); }
  float mu = s * (1.f / 512.f);
  float var = s2 * (1.f / 512.f) - mu * mu;
  float rs = rsqrtf(var + 1e-5f);
  int c0 = l * 8;
  float* orow = out + (size_t)row * 512;
  #pragma unroll
  for (int i = 0; i < 8; i++)
    orow[c0 + i] = (v[i] - mu) * rs * g[c0 + i] + be[c0 + i];
}

// ---------------- launch ----------------

extern "C" void kernel_launch(void* const* d_in, const int* in_sizes, int n_in,
                              void* d_out, int out_size, void* d_ws, size_t ws_size,
                              hipStream_t stream){
  (void)in_sizes; (void)n_in; (void)out_size; (void)ws_size;
  const float* x    = (const float*)d_in[0];
  const float* gw   = (const float*)d_in[1];
  const float* Wf   = (const float*)d_in[2];
  const float* bWf  = (const float*)d_in[3];
  const float* Uf   = (const float*)d_in[4];
  const float* bUf  = (const float*)d_in[5];
  const float* Wb   = (const float*)d_in[6];
  const float* bWb  = (const float*)d_in[7];
  const float* Ub   = (const float*)d_in[8];
  const float* bUb  = (const float*)d_in[9];
  const float* inw  = (const float*)d_in[10];
  const float* inb  = (const float*)d_in[11];
  const float* outw = (const float*)d_in[12];
  const float* outb = (const float*)d_in[13];
  const float* gam  = (const float*)d_in[14];
  const float* bet  = (const float*)d_in[15];
  char* ws = (char*)d_ws;

  size_t o = 0;
  auto take = [&](size_t bytes){ size_t r = o; o += (bytes + 255) & ~(size_t)255; return r; };
  size_t o_xb   = take(16384ULL * 256 * 2);
  size_t o_wt   = take(2560ULL * 256 * 2);
  size_t o_bias = take(2560ULL * 4);
  size_t o_inw  = take(1536ULL * 512 * 2);
  size_t o_outw = take(512ULL * 512 * 2);
  size_t o_upk  = take(4ULL * 160 * 512 * 4);
  size_t o_hx   = take(128ULL * 2 * 64 * 4);
  size_t o_flag = take(1024);
  size_t o_hcat = take(16384ULL * 512 * 2);
  size_t o_xg   = take(16384ULL * 2560 * 2);   // later reused: qkv (base), attno (+50331648)
  size_t o_vt   = take(128ULL * 128 * 512 * 2);
  size_t o_S    = take(128ULL * 512 * 512 * 2); // later reused: preln (f32)
  size_t o_qkv  = o_xg;
  size_t o_attn = o_xg + 16384ULL * 1536 * 2;
  size_t o_pre  = o_S;

  u16* xb     = (u16*)(ws + o_xb);
  u16* Wt     = (u16*)(ws + o_wt);
  float* bWU  = (float*)(ws + o_bias);
  u16* inwb   = (u16*)(ws + o_inw);
  u16* outwb  = (u16*)(ws + o_outw);
  u32* Upk    = (u32*)(ws + o_upk);
  u32* hx     = (u32*)(ws + o_hx);
  u32* flg    = (u32*)(ws + o_flag);
  u16* hcat   = (u16*)(ws + o_hcat);
  u16* xgb    = (u16*)(ws + o_xg);
  u16* qkv    = (u16*)(ws + o_qkv);
  u16* attn   = (u16*)(ws + o_attn);
  u16* Vt     = (u16*)(ws + o_vt);
  u16* S      = (u16*)(ws + o_S);
  float* pre  = (float*)(ws + o_pre);

  hipMemsetAsync(flg, 0, 1024, stream);
  conv_bf16_k<<<4096, 256, 0, stream>>>(x, xb, 16384 * 256);
  conv_bf16_k<<<1024, 256, 0, stream>>>(inw, inwb, 1536 * 512);
  conv_bf16_k<<<512, 256, 0, stream>>>(outw, outwb, 512 * 512);
  prep_wt_k<<<2560, 256, 0, stream>>>(Wf, Wb, bWf, bWb, bUf, bUb, Wt, bWU);
  prep_upk_k<<<1280, 256, 0, stream>>>(Uf, Ub, Upk);

  // xg = x @ Wt^T + (bW+bU), f16 out, [16384][2560]
  gemm_bt<2><<<dim3(2560, 1), 256, 0, stream>>>(xb, Wt, (void*)xgb, bWU,
      16384, 2560, 256, 256, 256, 2560, 0, 0, 0, 0, 0, 0, 1, 1.f);

  lstm_rec<<<128, 512, 0, stream>>>(xgb, Upk, gw, hcat, hx, flg);

  // qkv = hcat @ in_proj_w^T + b, bf16, [16384][1536]
  gemm_bt<1><<<dim3(1536, 1), 256, 0, stream>>>(hcat, inwb, (void*)qkv, inb,
      16384, 1536, 512, 512, 512, 1536, 0, 0, 0, 0, 0, 0, 1, 1.f);

  transpose_v_k<<<dim3(128, 16, 4), dim3(32, 8), 0, stream>>>(qkv, Vt);

  // scores: per (b,h): Q[512,128] @ K^T -> S bf16 [bh][512][512], scaled
  gemm_bt<1><<<dim3(16, 128), 256, 0, stream>>>(qkv, qkv + 512, (void*)S, nullptr,
      512, 512, 128, 1536, 1536, 512,
      786432LL, 128LL, 786432LL, 128LL, 1048576LL, 262144LL, 4, 0.08838834764831845f);

  softmax_rows<<<16384, 256, 0, stream>>>(S);

  // PV: P[512,512] @ Vt^T -> attno[b][t][h*128+d] bf16
  gemm_bt<1><<<dim3(4, 128), 256, 0, stream>>>(S, Vt, (void*)attn, nullptr,
      512, 128, 512, 512, 512, 512,
      1048576LL, 262144LL, 262144LL, 65536LL, 262144LL, 128LL, 4, 1.f);

  // out proj: attno @ out_w^T + b -> preln f32
  gemm_bt<0><<<dim3(512, 1), 256, 0, stream>>>(attn, outwb, (void*)pre, outb,
      16384, 512, 512, 512, 512, 512, 0, 0, 0, 0, 0, 0, 1, 1.f);

  ln_rows<<<4096, 256, 0, stream>>>(pre, gam, bet, (float*)d_out);
}

// Round 2
// 2156.272 us; speedup vs baseline: 1.5459x; 1.5459x over previous
//
#include <hip/hip_runtime.h>

typedef unsigned int u32;
typedef unsigned short u16;
typedef unsigned long long u64;
typedef float floatx4 __attribute__((ext_vector_type(4)));
typedef __bf16 bf16x8 __attribute__((ext_vector_type(8)));
typedef _Float16 f16x8 __attribute__((ext_vector_type(8)));

#define DEV __device__ __forceinline__

DEV u16 f2bf(float f){
  u32 u = __builtin_bit_cast(u32, f);
  u += 0x7FFFu + ((u >> 16) & 1u);
  return (u16)(u >> 16);
}
DEV float bf2f(u16 h){ u32 u = ((u32)h) << 16; return __builtin_bit_cast(float, u); }
DEV u16 f2h_bits(float f){ return __builtin_bit_cast(u16, (_Float16)f); }
DEV float h_bits2f(u16 h){ return (float)__builtin_bit_cast(_Float16, h); }
DEV float sigm(float x){ return 1.f / (1.f + __expf(-x)); }
DEV float tanh_(float x){
  float ax = fabsf(x);
  float e = __expf(-2.f * ax);
  float r = (1.f - e) / (1.f + e);
  return x < 0.f ? -r : r;
}

// ---------------- prep kernels ----------------

__global__ __launch_bounds__(256) void conv_bf16_k(const float* __restrict__ src, u16* __restrict__ dst, int n){
  for (int i = blockIdx.x * 256 + threadIdx.x; i < n; i += gridDim.x * 256)
    dst[i] = f2bf(src[i]);
}

// Wt[n][k] (n = dir*1280 + g*256 + h, k = i), bf16; biasWU[n] = bW+bU
__global__ __launch_bounds__(256) void prep_wt_k(const float* __restrict__ Wf, const float* __restrict__ Wb,
                                                 const float* __restrict__ bWf, const float* __restrict__ bWb,
                                                 const float* __restrict__ bUf, const float* __restrict__ bUb,
                                                 u16* __restrict__ Wt, float* __restrict__ biasWU){
  int idx = blockIdx.x * 256 + threadIdx.x;
  if (idx >= 2560 * 256) return;
  int n = idx >> 8, k = idx & 255;
  int dir = n / 1280, rr = n - dir * 1280, g = rr >> 8, hc = rr & 255;
  const float* W = dir ? Wb : Wf;
  Wt[idx] = f2bf(W[(g * 256 + k) * 256 + hc]);
  if (k == 0)
    biasWU[n] = (dir ? bWb : bWf)[g * 256 + hc] + (dir ? bUb : bUf)[g * 256 + hc];
}

// U MFMA B-fragments, f16. Linear index: ((((dir*2+ch)*8 + w)*40 + c)*64 + l) -> uint4 (8 halves)
// c = g*8 + slot; slot<4 -> own ksteps (ch*4+slot), else partner ((1-ch)*4+slot-4)
__global__ __launch_bounds__(256) void prep_ufrag(const float* __restrict__ Uf, const float* __restrict__ Ub,
                                                  uint4* __restrict__ out){
  int cid = blockIdx.x * 256 + threadIdx.x;
  if (cid >= 163840) return;
  int l = cid & 63;
  int c = (cid >> 6) % 40;
  int w = ((cid >> 6) / 40) % 8;
  int ch = ((cid >> 6) / 320) % 2;
  int dir = (cid >> 6) / 640;
  int g = c >> 3, slot = c & 7;
  int ks = (slot < 4) ? (ch * 4 + slot) : ((1 - ch) * 4 + (slot - 4));
  int colj = ch * 128 + w * 16 + (l & 15);
  const float* U = dir ? Ub : Uf;
  u32 hv[8];
  #pragma unroll
  for (int e = 0; e < 8; e++){
    int k = ks * 32 + (l >> 4) * 8 + e;
    hv[e] = f2h_bits(U[((size_t)g * 256 + k) * 256 + colj]);
  }
  uint4 o;
  o.x = hv[0] | (hv[1] << 16); o.y = hv[2] | (hv[3] << 16);
  o.z = hv[4] | (hv[5] << 16); o.w = hv[6] | (hv[7] << 16);
  out[cid] = o;
}

// Vt[bh][d][kt] from qkv[b][kt][1024 + h*128 + d]
__global__ __launch_bounds__(256) void transpose_v_k(const u16* __restrict__ qkv, u16* __restrict__ Vt){
  __shared__ u16 tile[32][33];
  int bh = blockIdx.x, bb = bh >> 2, h = bh & 3;
  int kt0 = blockIdx.y << 5, d0 = blockIdx.z << 5;
  int tx = threadIdx.x, ty = threadIdx.y;
  for (int i = ty; i < 32; i += 8)
    tile[i][tx] = qkv[(size_t)(bb * 512 + kt0 + i) * 1536 + 1024 + h * 128 + d0 + tx];
  __syncthreads();
  for (int i = ty; i < 32; i += 8)
    Vt[((size_t)bh * 128 + d0 + i) * 512 + kt0 + tx] = tile[tx][i];
}

// ---------------- GEMM (A[M,K] row-major bf16, Bt[N,K] row-major bf16) ----------------
// OM: 0=f32, 1=bf16, 2=f16

template<int OM>
__global__ __launch_bounds__(256) void gemm_bt(const u16* __restrict__ A, const u16* __restrict__ Bt,
                                               void* __restrict__ C, const float* __restrict__ bias,
                                               int M, int N, int K, int lda, int ldb, int ldc,
                                               long long aB1, long long aB2, long long bB1, long long bB2,
                                               long long cB1, long long cB2, int nb2, float scale){
  int tilesN = N >> 7;
  int bz = blockIdx.y;
  int b1 = bz / nb2, b2 = bz - b1 * nb2;
  const u16* Ab = A + (size_t)(b1 * aB1 + b2 * aB2);
  const u16* Bb = Bt + (size_t)(b1 * bB1 + b2 * bB2);
  size_t cOff = (size_t)(b1 * cB1 + b2 * cB2);
  int tm = blockIdx.x / tilesN, tn = blockIdx.x - tm * tilesN;
  int m0 = tm << 7, n0 = tn << 7;
  __shared__ u16 As[128 * 64];
  __shared__ u16 Bs[128 * 64];
  int t = threadIdx.x;
  int wave = t >> 6, lane = t & 63;
  int wr = wave >> 1, wc = wave & 1;
  int l15 = lane & 15, l4 = lane >> 4;
  floatx4 acc[4][4] = {};
  for (int k0 = 0; k0 < K; k0 += 64){
    #pragma unroll
    for (int i = 0; i < 4; i++){
      int chunk = t + (i << 8);
      int r = chunk >> 3, cx = chunk & 7;
      int sc = ((cx ^ (r & 7)) << 3);
      *(uint4*)(&As[(r << 6) + sc]) = *(const uint4*)(&Ab[(size_t)(m0 + r) * lda + k0 + (cx << 3)]);
      *(uint4*)(&Bs[(r << 6) + sc]) = *(const uint4*)(&Bb[(size_t)(n0 + r) * ldb + k0 + (cx << 3)]);
    }
    __syncthreads();
    #pragma unroll
    for (int kk = 0; kk < 2; kk++){
      bf16x8 af[4], bf[4];
      int co = (kk << 2) + l4;
      #pragma unroll
      for (int mi = 0; mi < 4; mi++){
        int r = (wr << 6) + (mi << 4) + l15;
        af[mi] = __builtin_bit_cast(bf16x8, *(const uint4*)(&As[(r << 6) + ((co ^ (r & 7)) << 3)]));
      }
      #pragma unroll
      for (int ni = 0; ni < 4; ni++){
        int r = (wc << 6) + (ni << 4) + l15;
        bf[ni] = __builtin_bit_cast(bf16x8, *(const uint4*)(&Bs[(r << 6) + ((co ^ (r & 7)) << 3)]));
      }
      #pragma unroll
      for (int mi = 0; mi < 4; mi++)
        #pragma unroll
        for (int ni = 0; ni < 4; ni++)
          acc[mi][ni] = __builtin_amdgcn_mfma_f32_16x16x32_bf16(af[mi], bf[ni], acc[mi][ni], 0, 0, 0);
    }
    __syncthreads();
  }
  #pragma unroll
  for (int mi = 0; mi < 4; mi++){
    int rowb = m0 + (wr << 6) + (mi << 4) + (l4 << 2);
    #pragma unroll
    for (int ni = 0; ni < 4; ni++){
      int col = n0 + (wc << 6) + (ni << 4) + l15;
      float bv = bias ? bias[col] : 0.f;
      #pragma unroll
      for (int r = 0; r < 4; r++){
        float val = acc[mi][ni][r] * scale + bv;
        size_t off = cOff + (size_t)(rowb + r) * ldc + col;
        if (OM == 0) ((float*)C)[off] = val;
        else if (OM == 1) ((u16*)C)[off] = f2bf(val);
        else ((u16*)C)[off] = f2h_bits(val);
      }
    }
  }
}

// ---------------- LSTM recurrence, MFMA-based ----------------
// 8 WGs = dir(2) x colhalf(2) x bhalf(2), 512 threads (8 waves).
// Per WG: U-slice [5][256][128] f16 register-resident as 40 uint4 B-frags/thread.
// Per step: g[16b, 5x128] = h[16,256] @ U via mfma_f32_16x16x32_f16 (wave w owns cols w*16..+16
// of all 5 gates); gates computed in-register on the C layout; pairwise h-exchange (4KB)
// through LLC with RELAXED agent atomics only (barrier vmcnt-drain orders data before flag).

__global__ __launch_bounds__(512, 2) void lstm_rec2(const u16* __restrict__ xg, const uint4* __restrict__ Ufr,
                                                    const float* __restrict__ dw, u16* __restrict__ hcat,
                                                    u64* __restrict__ mbox, u32* __restrict__ flags){
  int bid = blockIdx.x;
  int ch = bid & 1, dir = (bid >> 1) & 1, bh = bid >> 2;
  int pbid = bid ^ 1;
  int t = threadIdx.x;
  int w = t >> 6, l = t & 63;
  int l15 = l & 15, l4 = l >> 4;
  int jl = w * 16 + l15;            // own col 0..127
  int col = ch * 128 + jl;          // global h-column
  __shared__ __align__(16) char hA[8192];   // h[16 rows][256 cols] f16, row stride 512B, XOR swizzle
  for (int i = t; i < 2048; i += 512) ((u32*)hA)[i] = 0;
  const uint4* ub = Ufr + ((size_t)((dir * 2 + ch) * 8 + w) * 40) * 64 + l;
  uint4 uf[40];
  #pragma unroll
  for (int c = 0; c < 40; c++) uf[c] = ub[c * 64];
  float cst[4] = {0.f, 0.f, 0.f, 0.f};
  int kbOwn = ch * 256;             // byte base of own k-region within a row
  int kbPar = 256 - kbOwn;
  int rowB = l15 * 512;
  int swzR = (l15 & 7) << 4;
  __syncthreads();
  for (int s = 0; s < 512; s++){
    int ts = dir ? (511 - s) : s;
    // prefetch x-gate contributions + dw (consumed in gate phase)
    u16 xv[5][4]; float dv[4];
    #pragma unroll
    for (int r = 0; r < 4; r++){
      int b = bh * 16 + l4 * 4 + r;
      const u16* xrr = xg + ((size_t)b * 512 + ts) * 2560 + dir * 1280 + col;
      #pragma unroll
      for (int g = 0; g < 5; g++) xv[g][r] = xrr[g * 256];
      dv[r] = dw[((size_t)b * 512 + ts) * 256 + col];
    }
    floatx4 acc[5] = {};
    // phase A: own-half ksteps (no partner dependency)
    #pragma unroll
    for (int i = 0; i < 4; i++){
      f16x8 af = *(const f16x8*)(hA + rowB + ((kbOwn + i * 64 + l4 * 16) ^ swzR));
      #pragma unroll
      for (int g = 0; g < 5; g++)
        acc[g] = __builtin_amdgcn_mfma_f32_16x16x32_f16(af, __builtin_bit_cast(f16x8, uf[g * 8 + i]), acc[g], 0, 0, 0);
    }
    // phase B: import partner h (step s-1)
    if (s > 0){
      int guard = 0;
      while (__hip_atomic_load(&flags[pbid], __ATOMIC_RELAXED, __HIP_MEMORY_SCOPE_AGENT) < (u32)s){
        __builtin_amdgcn_s_sleep(1);
        if (++guard > (1 << 15)) break;
      }
      u64 dvv = __hip_atomic_load(&mbox[((size_t)pbid * 2 + ((s - 1) & 1)) * 512 + t],
                                  __ATOMIC_RELAXED, __HIP_MEMORY_SCOPE_AGENT);
      int j = t >> 2, bg = t & 3;
      #pragma unroll
      for (int r2 = 0; r2 < 4; r2++){
        int bl = bg * 4 + r2;
        *(u16*)(hA + bl * 512 + ((kbPar + j * 2) ^ ((bl & 7) << 4))) = (u16)(dvv >> (16 * r2));
      }
    }
    __syncthreads();                 // partner region ready
    // phase C: partner-half ksteps
    #pragma unroll
    for (int i = 0; i < 4; i++){
      f16x8 af = *(const f16x8*)(hA + rowB + ((kbPar + i * 64 + l4 * 16) ^ swzR));
      #pragma unroll
      for (int g = 0; g < 5; g++)
        acc[g] = __builtin_amdgcn_mfma_f32_16x16x32_f16(af, __builtin_bit_cast(f16x8, uf[g * 8 + 4 + i]), acc[g], 0, 0, 0);
    }
    // gates, in-register on C layout: lane owns col jl, rows b = bh*16 + l4*4 + r
    u16 hh[4]; float hf[4];
    #pragma unroll
    for (int r = 0; r < 4; r++){
      float gi = acc[0][r] + h_bits2f(xv[0][r]);
      float gf = acc[1][r] + h_bits2f(xv[1][r]);
      float go = acc[2][r] + h_bits2f(xv[2][r]);
      float gc = acc[3][r] + h_bits2f(xv[3][r]);
      float gs = acc[4][r] + h_bits2f(xv[4][r]);
      float iv = sigm(gi), fv = sigm(gf), ov = sigm(go);
      float chat = tanh_(gc);
      float sv = sigm(gs) * dv[r];
      cst[r] = fv * cst[r] + iv * chat * sv;
      hf[r] = ov * tanh_(cst[r]);
      hh[r] = f2h_bits(hf[r]);
    }
    // phase E: post mailbox (relaxed; drained by the barrier's vmcnt(0) in every wave)
    u64 pk = (u64)hh[0] | ((u64)hh[1] << 16) | ((u64)hh[2] << 32) | ((u64)hh[3] << 48);
    __hip_atomic_store(&mbox[((size_t)bid * 2 + (s & 1)) * 512 + (jl * 4 + l4)], pk,
                       __ATOMIC_RELAXED, __HIP_MEMORY_SCOPE_AGENT);
    // own h into hA
    #pragma unroll
    for (int r = 0; r < 4; r++){
      int bl = l4 * 4 + r;
      *(u16*)(hA + bl * 512 + ((kbOwn + jl * 2) ^ ((bl & 7) << 4))) = hh[r];
    }
    __syncthreads();                 // drains LDS writes + mailbox stores (vmcnt 0) in ALL waves
    if (t == 0)
      __hip_atomic_store(&flags[bid], (u32)(s + 1), __ATOMIC_RELAXED, __HIP_MEMORY_SCOPE_AGENT);
    // hcat (fire and forget)
    #pragma unroll
    for (int r = 0; r < 4; r++){
      int b = bh * 16 + l4 * 4 + r;
      hcat[((size_t)b * 512 + ts) * 512 + dir * 256 + col] = f2bf(hf[r]);
    }
  }
}

// ---------------- softmax (in-place bf16 rows of 512) ----------------

__global__ __launch_bounds__(256) void softmax_rows(u16* __restrict__ S){
  int row = blockIdx.x * 4 + (threadIdx.x >> 6);
  int l = threadIdx.x & 63;
  u16* r = S + (size_t)row * 512;
  uint4 v = *(const uint4*)(r + l * 8);
  u32 wsv[4] = {v.x, v.y, v.z, v.w};
  float f[8];
  #pragma unroll
  for (int i = 0; i < 4; i++){
    f[2 * i] = bf2f((u16)(wsv[i] & 0xFFFF));
    f[2 * i + 1] = bf2f((u16)(wsv[i] >> 16));
  }
  float mx = f[0];
  #pragma unroll
  for (int i = 1; i < 8; i++) mx = fmaxf(mx, f[i]);
  for (int m = 1; m < 64; m <<= 1) mx = fmaxf(mx, __shfl_xor(mx, m, 64));
  float e[8], s = 0.f;
  #pragma unroll
  for (int i = 0; i < 8; i++){ e[i] = __expf(f[i] - mx); s += e[i]; }
  for (int m = 1; m < 64; m <<= 1) s += __shfl_xor(s, m, 64);
  float inv = 1.f / s;
  uint4 o;
  u32 ov[4];
  #pragma unroll
  for (int i = 0; i < 4; i++)
    ov[i] = (u32)f2bf(e[2 * i] * inv) | ((u32)f2bf(e[2 * i + 1] * inv) << 16);
  o.x = ov[0]; o.y = ov[1]; o.z = ov[2]; o.w = ov[3];
  *(uint4*)(r + l * 8) = o;
}

// ---------------- layernorm (rows of 512, f32) ----------------

__global__ __launch_bounds__(256) void ln_rows(const float* __restrict__ X, const float* __restrict__ g,
                                               const float* __restrict__ be, float* __restrict__ out){
  int row = blockIdx.x * 4 + (threadIdx.x >> 6);
  int l = threadIdx.x & 63;
  const floatx4* p = (const floatx4*)(X + (size_t)row * 512);
  floatx4 aa = p[l * 2], bb = p[l * 2 + 1];
  float v[8];
  #pragma unroll
  for (int i = 0; i < 4; i++){ v[i] = aa[i]; v[4 + i] = bb[i]; }
  float s = 0.f, s2 = 0.f;
  #pragma unroll
  for (int i = 0; i < 8; i++){ s += v[i]; s2 += v[i] * v[i]; }
  for (int m = 1; m < 64; m <<= 1){ s += __shfl_xor(s, m, 64); s2 += __shfl_xor(s2, m, 64); }
  float mu = s * (1.f / 512.f);
  float var = s2 * (1.f / 512.f) - mu * mu;
  float rs = rsqrtf(var + 1e-5f);
  int c0 = l * 8;
  float* orow = out + (size_t)row * 512;
  #pragma unroll
  for (int i = 0; i < 8; i++)
    orow[c0 + i] = (v[i] - mu) * rs * g[c0 + i] + be[c0 + i];
}

// ---------------- launch ----------------

extern "C" void kernel_launch(void* const* d_in, const int* in_sizes, int n_in,
                              void* d_out, int out_size, void* d_ws, size_t ws_size,
                              hipStream_t stream){
  (void)in_sizes; (void)n_in; (void)out_size; (void)ws_size;
  const float* x    = (const float*)d_in[0];
  const float* gw   = (const float*)d_in[1];
  const float* Wf   = (const float*)d_in[2];
  const float* bWf  = (const float*)d_in[3];
  const float* Uf   = (const float*)d_in[4];
  const float* bUf  = (const float*)d_in[5];
  const float* Wb   = (const float*)d_in[6];
  const float* bWb  = (const float*)d_in[7];
  const float* Ub   = (const float*)d_in[8];
  const float* bUb  = (const float*)d_in[9];
  const float* inw  = (const float*)d_in[10];
  const float* inb  = (const float*)d_in[11];
  const float* outw = (const float*)d_in[12];
  const float* outb = (const float*)d_in[13];
  const float* gam  = (const float*)d_in[14];
  const float* bet  = (const float*)d_in[15];
  char* ws = (char*)d_ws;

  size_t o = 0;
  auto take = [&](size_t bytes){ size_t r = o; o += (bytes + 255) & ~(size_t)255; return r; };
  size_t o_xb   = take(16384ULL * 256 * 2);
  size_t o_wt   = take(2560ULL * 256 * 2);
  size_t o_bias = take(2560ULL * 4);
  size_t o_inw  = take(1536ULL * 512 * 2);
  size_t o_outw = take(512ULL * 512 * 2);
  size_t o_ufr  = take(163840ULL * 16);
  size_t o_mbox = take(8ULL * 2 * 512 * 8);
  size_t o_flag = take(1024);
  size_t o_hcat = take(16384ULL * 512 * 2);
  size_t o_xg   = take(16384ULL * 2560 * 2);   // later reused: qkv (base), attno (+48MB)
  size_t o_vt   = take(128ULL * 128 * 512 * 2);
  size_t o_S    = take(128ULL * 512 * 512 * 2); // later reused: preln (f32)
  size_t o_qkv  = o_xg;
  size_t o_attn = o_xg + 16384ULL * 1536 * 2;
  size_t o_pre  = o_S;

  u16* xb     = (u16*)(ws + o_xb);
  u16* Wt     = (u16*)(ws + o_wt);
  float* bWU  = (float*)(ws + o_bias);
  u16* inwb   = (u16*)(ws + o_inw);
  u16* outwb  = (u16*)(ws + o_outw);
  uint4* Ufr  = (uint4*)(ws + o_ufr);
  u64* mbox   = (u64*)(ws + o_mbox);
  u32* flg    = (u32*)(ws + o_flag);
  u16* hcat   = (u16*)(ws + o_hcat);
  u16* xgb    = (u16*)(ws + o_xg);
  u16* qkv    = (u16*)(ws + o_qkv);
  u16* attn   = (u16*)(ws + o_attn);
  u16* Vt     = (u16*)(ws + o_vt);
  u16* S      = (u16*)(ws + o_S);
  float* pre  = (float*)(ws + o_pre);

  hipMemsetAsync(flg, 0, 1024, stream);
  conv_bf16_k<<<4096, 256, 0, stream>>>(x, xb, 16384 * 256);
  conv_bf16_k<<<1024, 256, 0, stream>>>(inw, inwb, 1536 * 512);
  conv_bf16_k<<<512, 256, 0, stream>>>(outw, outwb, 512 * 512);
  prep_wt_k<<<2560, 256, 0, stream>>>(Wf, Wb, bWf, bWb, bUf, bUb, Wt, bWU);
  prep_ufrag<<<640, 256, 0, stream>>>(Uf, Ub, Ufr);

  // xg = x @ Wt^T + (bW+bU), f16 out, [16384][2560]
  gemm_bt<2><<<dim3(2560, 1), 256, 0, stream>>>(xb, Wt, (void*)xgb, bWU,
      16384, 2560, 256, 256, 256, 2560, 0, 0, 0, 0, 0, 0, 1, 1.f);

  lstm_rec2<<<8, 512, 0, stream>>>(xgb, Ufr, gw, hcat, mbox, flg);

  // qkv = hcat @ in_proj_w^T + b, bf16, [16384][1536]
  gemm_bt<1><<<dim3(1536, 1), 256, 0, stream>>>(hcat, inwb, (void*)qkv, inb,
      16384, 1536, 512, 512, 512, 1536, 0, 0, 0, 0, 0, 0, 1, 1.f);

  transpose_v_k<<<dim3(128, 16, 4), dim3(32, 8), 0, stream>>>(qkv, Vt);

  // scores: per (b,h): Q[512,128] @ K^T -> S bf16 [bh][512][512], scaled
  gemm_bt<1><<<dim3(16, 128), 256, 0, stream>>>(qkv, qkv + 512, (void*)S, nullptr,
      512, 512, 128, 1536, 1536, 512,
      786432LL, 128LL, 786432LL, 128LL, 1048576LL, 262144LL, 4, 0.08838834764831845f);

  softmax_rows<<<16384, 256, 0, stream>>>(S);

  // PV: P[512,512] @ Vt^T -> attno[b][t][h*128+d] bf16
  gemm_bt<1><<<dim3(4, 128), 256, 0, stream>>>(S, Vt, (void*)attn, nullptr,
      512, 128, 512, 512, 512, 512,
      1048576LL, 262144LL, 262144LL, 65536LL, 262144LL, 128LL, 4, 1.f);

  // out proj: attno @ out_w^T + b -> preln f32
  gemm_bt<0><<<dim3(512, 1), 256, 0, stream>>>(attn, outwb, (void*)pre, outb,
      16384, 512, 512, 512, 512, 512, 0, 0, 0, 0, 0, 0, 1, 1.f);

  ln_rows<<<4096, 256, 0, stream>>>(pre, gam, bet, (float*)d_out);
}

// Round 3
// 2034.655 us; speedup vs baseline: 1.6383x; 1.0598x over previous
//
#include <hip/hip_runtime.h>

typedef unsigned int u32;
typedef unsigned short u16;
typedef unsigned long long u64;
typedef float floatx4 __attribute__((ext_vector_type(4)));
typedef __bf16 bf16x8 __attribute__((ext_vector_type(8)));
typedef _Float16 f16x8 __attribute__((ext_vector_type(8)));

#define DEV __device__ __forceinline__

DEV u16 f2bf(float f){
  u32 u = __builtin_bit_cast(u32, f);
  u += 0x7FFFu + ((u >> 16) & 1u);
  return (u16)(u >> 16);
}
DEV float bf2f(u16 h){ u32 u = ((u32)h) << 16; return __builtin_bit_cast(float, u); }
DEV u16 f2h_bits(float f){ return __builtin_bit_cast(u16, (_Float16)f); }
DEV float h_bits2f(u16 h){ return (float)__builtin_bit_cast(_Float16, h); }
DEV float sigm(float x){ return 1.f / (1.f + __expf(-x)); }
DEV float tanh_(float x){
  float ax = fabsf(x);
  float e = __expf(-2.f * ax);
  float r = (1.f - e) / (1.f + e);
  return x < 0.f ? -r : r;
}
// LDS-only barrier: orders ds_read/ds_write across waves WITHOUT draining vmcnt
// (global stores keep flying; sentinel protocol makes store order irrelevant).
DEV void bar_lds(){
  __builtin_amdgcn_sched_barrier(0);
  asm volatile("s_waitcnt lgkmcnt(0)" ::: "memory");
  __builtin_amdgcn_s_barrier();
  __builtin_amdgcn_sched_barrier(0);
}

// ---------------- prep kernels ----------------

__global__ __launch_bounds__(256) void conv_bf16_k(const float* __restrict__ src, u16* __restrict__ dst, int n){
  for (int i = blockIdx.x * 256 + threadIdx.x; i < n; i += gridDim.x * 256)
    dst[i] = f2bf(src[i]);
}

// Wt[n][k] (n = dir*1280 + g*256 + h, k = i), bf16; biasWU[n] = bW+bU
__global__ __launch_bounds__(256) void prep_wt_k(const float* __restrict__ Wf, const float* __restrict__ Wb,
                                                 const float* __restrict__ bWf, const float* __restrict__ bWb,
                                                 const float* __restrict__ bUf, const float* __restrict__ bUb,
                                                 u16* __restrict__ Wt, float* __restrict__ biasWU){
  int idx = blockIdx.x * 256 + threadIdx.x;
  if (idx >= 2560 * 256) return;
  int n = idx >> 8, k = idx & 255;
  int dir = n / 1280, rr = n - dir * 1280, g = rr >> 8, hc = rr & 255;
  const float* W = dir ? Wb : Wf;
  Wt[idx] = f2bf(W[(g * 256 + k) * 256 + hc]);
  if (k == 0)
    biasWU[n] = (dir ? bWb : bWf)[g * 256 + hc] + (dir ? bUb : bUf)[g * 256 + hc];
}

// U MFMA B-fragments, f16. Linear index: ((((dir*2+ch)*8 + w)*40 + c)*64 + l) -> uint4 (8 halves)
// c = g*8 + slot; slot<4 -> own ksteps (ch*4+slot), else partner ((1-ch)*4+slot-4)
__global__ __launch_bounds__(256) void prep_ufrag(const float* __restrict__ Uf, const float* __restrict__ Ub,
                                                  uint4* __restrict__ out){
  int cid = blockIdx.x * 256 + threadIdx.x;
  if (cid >= 163840) return;
  int l = cid & 63;
  int c = (cid >> 6) % 40;
  int w = ((cid >> 6) / 40) % 8;
  int ch = ((cid >> 6) / 320) % 2;
  int dir = (cid >> 6) / 640;
  int g = c >> 3, slot = c & 7;
  int ks = (slot < 4) ? (ch * 4 + slot) : ((1 - ch) * 4 + (slot - 4));
  int colj = ch * 128 + w * 16 + (l & 15);
  const float* U = dir ? Ub : Uf;
  u32 hv[8];
  #pragma unroll
  for (int e = 0; e < 8; e++){
    int k = ks * 32 + (l >> 4) * 8 + e;
    hv[e] = f2h_bits(U[((size_t)g * 256 + k) * 256 + colj]);
  }
  uint4 o;
  o.x = hv[0] | (hv[1] << 16); o.y = hv[2] | (hv[3] << 16);
  o.z = hv[4] | (hv[5] << 16); o.w = hv[6] | (hv[7] << 16);
  out[cid] = o;
}

// Vt[bh][d][kt] from qkv[b][kt][1024 + h*128 + d]
__global__ __launch_bounds__(256) void transpose_v_k(const u16* __restrict__ qkv, u16* __restrict__ Vt){
  __shared__ u16 tile[32][33];
  int bh = blockIdx.x, bb = bh >> 2, h = bh & 3;
  int kt0 = blockIdx.y << 5, d0 = blockIdx.z << 5;
  int tx = threadIdx.x, ty = threadIdx.y;
  for (int i = ty; i < 32; i += 8)
    tile[i][tx] = qkv[(size_t)(bb * 512 + kt0 + i) * 1536 + 1024 + h * 128 + d0 + tx];
  __syncthreads();
  for (int i = ty; i < 32; i += 8)
    Vt[((size_t)bh * 128 + d0 + i) * 512 + kt0 + tx] = tile[tx][i];
}

// ---------------- GEMM (A[M,K] row-major bf16, Bt[N,K] row-major bf16) ----------------
// OM: 0=f32, 1=bf16, 2=f16

template<int OM>
__global__ __launch_bounds__(256) void gemm_bt(const u16* __restrict__ A, const u16* __restrict__ Bt,
                                               void* __restrict__ C, const float* __restrict__ bias,
                                               int M, int N, int K, int lda, int ldb, int ldc,
                                               long long aB1, long long aB2, long long bB1, long long bB2,
                                               long long cB1, long long cB2, int nb2, float scale){
  int tilesN = N >> 7;
  int bz = blockIdx.y;
  int b1 = bz / nb2, b2 = bz - b1 * nb2;
  const u16* Ab = A + (size_t)(b1 * aB1 + b2 * aB2);
  const u16* Bb = Bt + (size_t)(b1 * bB1 + b2 * bB2);
  size_t cOff = (size_t)(b1 * cB1 + b2 * cB2);
  int tm = blockIdx.x / tilesN, tn = blockIdx.x - tm * tilesN;
  int m0 = tm << 7, n0 = tn << 7;
  __shared__ u16 As[128 * 64];
  __shared__ u16 Bs[128 * 64];
  int t = threadIdx.x;
  int wave = t >> 6, lane = t & 63;
  int wr = wave >> 1, wc = wave & 1;
  int l15 = lane & 15, l4 = lane >> 4;
  floatx4 acc[4][4] = {};
  for (int k0 = 0; k0 < K; k0 += 64){
    #pragma unroll
    for (int i = 0; i < 4; i++){
      int chunk = t + (i << 8);
      int r = chunk >> 3, cx = chunk & 7;
      int sc = ((cx ^ (r & 7)) << 3);
      *(uint4*)(&As[(r << 6) + sc]) = *(const uint4*)(&Ab[(size_t)(m0 + r) * lda + k0 + (cx << 3)]);
      *(uint4*)(&Bs[(r << 6) + sc]) = *(const uint4*)(&Bb[(size_t)(n0 + r) * ldb + k0 + (cx << 3)]);
    }
    __syncthreads();
    #pragma unroll
    for (int kk = 0; kk < 2; kk++){
      bf16x8 af[4], bf[4];
      int co = (kk << 2) + l4;
      #pragma unroll
      for (int mi = 0; mi < 4; mi++){
        int r = (wr << 6) + (mi << 4) + l15;
        af[mi] = __builtin_bit_cast(bf16x8, *(const uint4*)(&As[(r << 6) + ((co ^ (r & 7)) << 3)]));
      }
      #pragma unroll
      for (int ni = 0; ni < 4; ni++){
        int r = (wc << 6) + (ni << 4) + l15;
        bf[ni] = __builtin_bit_cast(bf16x8, *(const uint4*)(&Bs[(r << 6) + ((co ^ (r & 7)) << 3)]));
      }
      #pragma unroll
      for (int mi = 0; mi < 4; mi++)
        #pragma unroll
        for (int ni = 0; ni < 4; ni++)
          acc[mi][ni] = __builtin_amdgcn_mfma_f32_16x16x32_bf16(af[mi], bf[ni], acc[mi][ni], 0, 0, 0);
    }
    __syncthreads();
  }
  #pragma unroll
  for (int mi = 0; mi < 4; mi++){
    int rowb = m0 + (wr << 6) + (mi << 4) + (l4 << 2);
    #pragma unroll
    for (int ni = 0; ni < 4; ni++){
      int col = n0 + (wc << 6) + (ni << 4) + l15;
      float bv = bias ? bias[col] : 0.f;
      #pragma unroll
      for (int r = 0; r < 4; r++){
        float val = acc[mi][ni][r] * scale + bv;
        size_t off = cOff + (size_t)(rowb + r) * ldc + col;
        if (OM == 0) ((float*)C)[off] = val;
        else if (OM == 1) ((u16*)C)[off] = f2bf(val);
        else ((u16*)C)[off] = f2h_bits(val);
      }
    }
  }
}

// ---------------- LSTM recurrence, MFMA + sentinel-mailbox ----------------
// 8 WGs = dir(2) x colhalf(2) x bhalf(2), 512 threads.
// Exchange: 512-deep mailbox in global; producer fires packed-h u64 relaxed store right
// after gates; consumer polls its own word for != SENTINEL (arrival IS the signal; poll
// returns the payload). Barriers are LDS-only (raw s_barrier + lgkmcnt) -> no vmcnt drains.

#define SENT 0xFFFFFFFFFFFFFFFFULL

__global__ __launch_bounds__(512, 2) void lstm_rec3(const u16* __restrict__ xg, const uint4* __restrict__ Ufr,
                                                    const float* __restrict__ dw, u16* __restrict__ hcat,
                                                    u64* __restrict__ mbox){
  int bid = blockIdx.x;
  int ch = bid & 1, dir = (bid >> 1) & 1, bh = bid >> 2;
  int pbid = bid ^ 1;
  int t = threadIdx.x;
  int w = t >> 6, l = t & 63;
  int l15 = l & 15, l4 = l >> 4;
  int jl = w * 16 + l15;            // own col 0..127
  int col = ch * 128 + jl;          // global h-column
  __shared__ __align__(16) char hA[8192];   // h[16 rows][256 cols] f16, row stride 512B, XOR swizzle
  for (int i = t; i < 2048; i += 512) ((u32*)hA)[i] = 0;
  const uint4* ub = Ufr + ((size_t)((dir * 2 + ch) * 8 + w) * 40) * 64 + l;
  uint4 uf[40];
  #pragma unroll
  for (int c = 0; c < 40; c++) uf[c] = ub[c * 64];
  float cst[4] = {0.f, 0.f, 0.f, 0.f};
  int kbOwn = ch * 256;             // byte base of own k-region within a row
  int kbPar = 256 - kbOwn;
  int rowB = l15 * 512;
  int swzR = (l15 & 7) << 4;
  __syncthreads();
  for (int s = 0; s < 512; s++){
    int ts = dir ? (511 - s) : s;
    // prefetch x-gate contributions + dw (consumed in gate phase; vmcnt waits there)
    u16 xv[5][4]; float dv[4];
    #pragma unroll
    for (int r = 0; r < 4; r++){
      int b = bh * 16 + l4 * 4 + r;
      const u16* xrr = xg + ((size_t)b * 512 + ts) * 2560 + dir * 1280 + col;
      #pragma unroll
      for (int g = 0; g < 5; g++) xv[g][r] = xrr[g * 256];
      dv[r] = dw[((size_t)b * 512 + ts) * 256 + col];
    }
    floatx4 acc[5] = {};
    // phase A: own-half ksteps (no partner dependency; MFMAs run while we poll)
    #pragma unroll
    for (int i = 0; i < 4; i++){
      f16x8 af = *(const f16x8*)(hA + rowB + ((kbOwn + i * 64 + l4 * 16) ^ swzR));
      #pragma unroll
      for (int g = 0; g < 5; g++)
        acc[g] = __builtin_amdgcn_mfma_f32_16x16x32_f16(af, __builtin_bit_cast(f16x8, uf[g * 8 + i]), acc[g], 0, 0, 0);
    }
    // phase B: poll partner h(s-1) — arrival of data IS the signal
    if (s > 0){
      u64 dvv;
      int guard = 0;
      const u64* wp = &mbox[((size_t)pbid * 512 + (s - 1)) * 512 + t];
      for (;;){
        dvv = __hip_atomic_load(wp, __ATOMIC_RELAXED, __HIP_MEMORY_SCOPE_AGENT);
        if (dvv != SENT) break;
        __builtin_amdgcn_s_sleep(1);
        if (++guard > (1 << 15)) break;
      }
      int j = t >> 2, bg = t & 3;
      #pragma unroll
      for (int r2 = 0; r2 < 4; r2++){
        int bl = bg * 4 + r2;
        *(u16*)(hA + bl * 512 + ((kbPar + j * 2) ^ ((bl & 7) << 4))) = (u16)(dvv >> (16 * r2));
      }
    }
    bar_lds();                       // partner region visible to all waves
    // phase C: partner-half ksteps
    #pragma unroll
    for (int i = 0; i < 4; i++){
      f16x8 af = *(const f16x8*)(hA + rowB + ((kbPar + i * 64 + l4 * 16) ^ swzR));
      #pragma unroll
      for (int g = 0; g < 5; g++)
        acc[g] = __builtin_amdgcn_mfma_f32_16x16x32_f16(af, __builtin_bit_cast(f16x8, uf[g * 8 + 4 + i]), acc[g], 0, 0, 0);
    }
    // gates, in-register on C layout: lane owns col jl, rows b = bh*16 + l4*4 + r
    u16 hh[4]; float hf[4];
    #pragma unroll
    for (int r = 0; r < 4; r++){
      float gi = acc[0][r] + h_bits2f(xv[0][r]);
      float gf = acc[1][r] + h_bits2f(xv[1][r]);
      float go = acc[2][r] + h_bits2f(xv[2][r]);
      float gc = acc[3][r] + h_bits2f(xv[3][r]);
      float gs = acc[4][r] + h_bits2f(xv[4][r]);
      float iv = sigm(gi), fv = sigm(gf), ov = sigm(go);
      float chat = tanh_(gc);
      float sv = sigm(gs) * dv[r];
      cst[r] = fv * cst[r] + iv * chat * sv;
      hf[r] = ov * tanh_(cst[r]);
      hh[r] = f2h_bits(hf[r]);
    }
    // fire mailbox store IMMEDIATELY — no drain, arrival signals the partner
    u64 pk = (u64)hh[0] | ((u64)hh[1] << 16) | ((u64)hh[2] << 32) | ((u64)hh[3] << 48);
    __hip_atomic_store(&mbox[((size_t)bid * 512 + s) * 512 + (jl * 4 + l4)], pk,
                       __ATOMIC_RELAXED, __HIP_MEMORY_SCOPE_AGENT);
    // hcat (fire and forget)
    #pragma unroll
    for (int r = 0; r < 4; r++){
      int b = bh * 16 + l4 * 4 + r;
      hcat[((size_t)b * 512 + ts) * 512 + dir * 256 + col] = f2bf(hf[r]);
    }
    // own h into hA
    #pragma unroll
    for (int r = 0; r < 4; r++){
      int bl = l4 * 4 + r;
      *(u16*)(hA + bl * 512 + ((kbOwn + jl * 2) ^ ((bl & 7) << 4))) = hh[r];
    }
    bar_lds();                       // own region visible before next step's phase A
  }
}

// ---------------- softmax (in-place bf16 rows of 512) ----------------

__global__ __launch_bounds__(256) void softmax_rows(u16* __restrict__ S){
  int row = blockIdx.x * 4 + (threadIdx.x >> 6);
  int l = threadIdx.x & 63;
  u16* r = S + (size_t)row * 512;
  uint4 v = *(const uint4*)(r + l * 8);
  u32 wsv[4] = {v.x, v.y, v.z, v.w};
  float f[8];
  #pragma unroll
  for (int i = 0; i < 4; i++){
    f[2 * i] = bf2f((u16)(wsv[i] & 0xFFFF));
    f[2 * i + 1] = bf2f((u16)(wsv[i] >> 16));
  }
  float mx = f[0];
  #pragma unroll
  for (int i = 1; i < 8; i++) mx = fmaxf(mx, f[i]);
  for (int m = 1; m < 64; m <<= 1) mx = fmaxf(mx, __shfl_xor(mx, m, 64));
  float e[8], s = 0.f;
  #pragma unroll
  for (int i = 0; i < 8; i++){ e[i] = __expf(f[i] - mx); s += e[i]; }
  for (int m = 1; m < 64; m <<= 1) s += __shfl_xor(s, m, 64);
  float inv = 1.f / s;
  uint4 o;
  u32 ov[4];
  #pragma unroll
  for (int i = 0; i < 4; i++)
    ov[i] = (u32)f2bf(e[2 * i] * inv) | ((u32)f2bf(e[2 * i + 1] * inv) << 16);
  o.x = ov[0]; o.y = ov[1]; o.z = ov[2]; o.w = ov[3];
  *(uint4*)(r + l * 8) = o;
}

// ---------------- layernorm (rows of 512, f32) ----------------

__global__ __launch_bounds__(256) void ln_rows(const float* __restrict__ X, const float* __restrict__ g,
                                               const float* __restrict__ be, float* __restrict__ out){
  int row = blockIdx.x * 4 + (threadIdx.x >> 6);
  int l = threadIdx.x & 63;
  const floatx4* p = (const floatx4*)(X + (size_t)row * 512);
  floatx4 aa = p[l * 2], bb = p[l * 2 + 1];
  float v[8];
  #pragma unroll
  for (int i = 0; i < 4; i++){ v[i] = aa[i]; v[4 + i] = bb[i]; }
  float s = 0.f, s2 = 0.f;
  #pragma unroll
  for (int i = 0; i < 8; i++){ s += v[i]; s2 += v[i] * v[i]; }
  for (int m = 1; m < 64; m <<= 1){ s += __shfl_xor(s, m, 64); s2 += __shfl_xor(s2, m, 64); }
  float mu = s * (1.f / 512.f);
  float var = s2 * (1.f / 512.f) - mu * mu;
  float rs = rsqrtf(var + 1e-5f);
  int c0 = l * 8;
  float* orow = out + (size_t)row * 512;
  #pragma unroll
  for (int i = 0; i < 8; i++)
    orow[c0 + i] = (v[i] - mu) * rs * g[c0 + i] + be[c0 + i];
}

// ---------------- launch ----------------

extern "C" void kernel_launch(void* const* d_in, const int* in_sizes, int n_in,
                              void* d_out, int out_size, void* d_ws, size_t ws_size,
                              hipStream_t stream){
  (void)in_sizes; (void)n_in; (void)out_size; (void)ws_size;
  const float* x    = (const float*)d_in[0];
  const float* gw   = (const float*)d_in[1];
  const float* Wf   = (const float*)d_in[2];
  const float* bWf  = (const float*)d_in[3];
  const float* Uf   = (const float*)d_in[4];
  const float* bUf  = (const float*)d_in[5];
  const float* Wb   = (const float*)d_in[6];
  const float* bWb  = (const float*)d_in[7];
  const float* Ub   = (const float*)d_in[8];
  const float* bUb  = (const float*)d_in[9];
  const float* inw  = (const float*)d_in[10];
  const float* inb  = (const float*)d_in[11];
  const float* outw = (const float*)d_in[12];
  const float* outb = (const float*)d_in[13];
  const float* gam  = (const float*)d_in[14];
  const float* bet  = (const float*)d_in[15];
  char* ws = (char*)d_ws;

  size_t o = 0;
  auto take = [&](size_t bytes){ size_t r = o; o += (bytes + 255) & ~(size_t)255; return r; };
  size_t o_xb   = take(16384ULL * 256 * 2);
  size_t o_wt   = take(2560ULL * 256 * 2);
  size_t o_bias = take(2560ULL * 4);
  size_t o_inw  = take(1536ULL * 512 * 2);
  size_t o_outw = take(512ULL * 512 * 2);
  size_t o_ufr  = take(163840ULL * 16);
  size_t o_mbox = take(8ULL * 512 * 512 * 8);   // 16 MB, sentinel-initialized per launch
  size_t o_hcat = take(16384ULL * 512 * 2);
  size_t o_xg   = take(16384ULL * 2560 * 2);   // later reused: qkv (base), attno (+48MB)
  size_t o_vt   = take(128ULL * 128 * 512 * 2);
  size_t o_S    = take(128ULL * 512 * 512 * 2); // later reused: preln (f32)
  size_t o_qkv  = o_xg;
  size_t o_attn = o_xg + 16384ULL * 1536 * 2;
  size_t o_pre  = o_S;

  u16* xb     = (u16*)(ws + o_xb);
  u16* Wt     = (u16*)(ws + o_wt);
  float* bWU  = (float*)(ws + o_bias);
  u16* inwb   = (u16*)(ws + o_inw);
  u16* outwb  = (u16*)(ws + o_outw);
  uint4* Ufr  = (uint4*)(ws + o_ufr);
  u64* mbox   = (u64*)(ws + o_mbox);
  u16* hcat   = (u16*)(ws + o_hcat);
  u16* xgb    = (u16*)(ws + o_xg);
  u16* qkv    = (u16*)(ws + o_qkv);
  u16* attn   = (u16*)(ws + o_attn);
  u16* Vt     = (u16*)(ws + o_vt);
  u16* S      = (u16*)(ws + o_S);
  float* pre  = (float*)(ws + o_pre);

  hipMemsetAsync(mbox, 0xFF, 8ULL * 512 * 512 * 8, stream);  // sentinel fill each call
  conv_bf16_k<<<4096, 256, 0, stream>>>(x, xb, 16384 * 256);
  conv_bf16_k<<<1024, 256, 0, stream>>>(inw, inwb, 1536 * 512);
  conv_bf16_k<<<512, 256, 0, stream>>>(outw, outwb, 512 * 512);
  prep_wt_k<<<2560, 256, 0, stream>>>(Wf, Wb, bWf, bWb, bUf, bUb, Wt, bWU);
  prep_ufrag<<<640, 256, 0, stream>>>(Uf, Ub, Ufr);

  // xg = x @ Wt^T + (bW+bU), f16 out, [16384][2560]
  gemm_bt<2><<<dim3(2560, 1), 256, 0, stream>>>(xb, Wt, (void*)xgb, bWU,
      16384, 2560, 256, 256, 256, 2560, 0, 0, 0, 0, 0, 0, 1, 1.f);

  lstm_rec3<<<8, 512, 0, stream>>>(xgb, Ufr, gw, hcat, mbox);

  // qkv = hcat @ in_proj_w^T + b, bf16, [16384][1536]
  gemm_bt<1><<<dim3(1536, 1), 256, 0, stream>>>(hcat, inwb, (void*)qkv, inb,
      16384, 1536, 512, 512, 512, 1536, 0, 0, 0, 0, 0, 0, 1, 1.f);

  transpose_v_k<<<dim3(128, 16, 4), dim3(32, 8), 0, stream>>>(qkv, Vt);

  // scores: per (b,h): Q[512,128] @ K^T -> S bf16 [bh][512][512], scaled
  gemm_bt<1><<<dim3(16, 128), 256, 0, stream>>>(qkv, qkv + 512, (void*)S, nullptr,
      512, 512, 128, 1536, 1536, 512,
      786432LL, 128LL, 786432LL, 128LL, 1048576LL, 262144LL, 4, 0.08838834764831845f);

  softmax_rows<<<16384, 256, 0, stream>>>(S);

  // PV: P[512,512] @ Vt^T -> attno[b][t][h*128+d] bf16
  gemm_bt<1><<<dim3(4, 128), 256, 0, stream>>>(S, Vt, (void*)attn, nullptr,
      512, 128, 512, 512, 512, 512,
      1048576LL, 262144LL, 262144LL, 65536LL, 262144LL, 128LL, 4, 1.f);

  // out proj: attno @ out_w^T + b -> preln f32
  gemm_bt<0><<<dim3(512, 1), 256, 0, stream>>>(attn, outwb, (void*)pre, outb,
      16384, 512, 512, 512, 512, 512, 0, 0, 0, 0, 0, 0, 1, 1.f);

  ln_rows<<<4096, 256, 0, stream>>>(pre, gam, bet, (float*)d_out);
}